// Round 10
// baseline (46.957 us; speedup 1.0000x reference)
//
#include <hip/hip_runtime.h>
#include <hip/hip_bf16.h>

#define HD 64
#define LSEQ 2048
#define NBATCH 1024
#define NSLOTS 8

// Single kernel, zero cross-block dependencies (R8-verified structure).
// 256 blocks x 512 threads (8 waves). Block handles rows [bid*4, bid*4+4).
//   Phase T (all waves): redundantly build the 64-token tables in LDS.
//     VALU floor = 1.57M FMA / (128 FMA/cy/CU) ~ 5.1us. Engineered vs R8:
//     all CUs busy, full unroll, per-lane LDS token rows (stride-65, free) x
//     wave-uniform weight rows (scalar s_loads, prefetched by the unroll).
//   Phase R: wave pair (w, w+4) -> row bid*4 + (w&3). Each wave histograms
//     half the row; attention is computed REDUNDANTLY by both waves (same
//     inputs -> identical values; duplicate LDS/global writes benign) so all
//     512 threads reach every __syncthreads (no divergent barriers).
//   All cross-phase LDS handoffs barrier-separated; LDS read back scalar
//   (no float4 punning on LDS — R6 lesson).
__global__ __launch_bounds__(512) void fused_kernel(
    const int* __restrict__ seq,
    const float* __restrict__ embed, const float* __restrict__ w1, const float* __restrict__ b1,
    const float* __restrict__ w2, const float* __restrict__ b2,
    const float* __restrict__ gamma, const float* __restrict__ beta,
    const float* __restrict__ gate_w, const float* __restrict__ gate_b,
    const float* __restrict__ qi_w, const float* __restrict__ qi_b,
    const float* __restrict__ sk_w, const float* __restrict__ sk_b,
    const float* __restrict__ qr_w, const float* __restrict__ qr_b,
    const float* __restrict__ out_w, const float* __restrict__ out_b,
    float* __restrict__ out)
{
    const int tid  = threadIdx.x;                         // 0..511
    const int w    = tid >> 6;                            // wave 0..7
    const int lane = tid & 63;
    const int wu   = __builtin_amdgcn_readfirstlane(w);   // SGPR wave id
    const int rw   = wu & 3;                              // row-slot 0..3
    const int h2   = wu >> 2;                             // seq half 0/1
    const int row  = blockIdx.x * 4 + rw;                 // this wave's batch row

    __shared__ float E [64][65];
    __shared__ float T1[64][129];
    __shared__ float X [64][65];
    __shared__ float H [64][65];
    __shared__ float QI[64][65];
    __shared__ float SK[64][65];
    __shared__ float score_s[64];
    __shared__ int   hist[8][64];
    __shared__ int   order_s[4][64];
    __shared__ int   slot_s[4][NSLOTS];
    __shared__ float rbuf[4][64];

    // ---- seq prefetch: wave covers tokens [h2*1024, h2*1024+1024) of row ----
    const int4* srow4 = (const int4*)(seq + (size_t)row * LSEQ);
    int4 q[4];
    #pragma unroll
    for (int i = 0; i < 4; ++i) q[i] = srow4[lane + 64 * i + 256 * h2];

    // ---- E stage: embed (4096 floats) -> LDS, coalesced ----
    #pragma unroll
    for (int k = 0; k < 8; ++k) {
        int idx = tid + 512 * k;
        E[idx >> 6][idx & 63] = embed[idx];
    }
    __syncthreads();

    // ---- Phase T1: relu(E @ w1^T + b1); wave owns j in [wu*16, wu*16+16) ----
    {
        const int j0 = wu * 16;
        float acc[16];
        #pragma unroll
        for (int jj = 0; jj < 16; ++jj) acc[jj] = b1[j0 + jj];
        #pragma unroll
        for (int c4 = 0; c4 < 4; ++c4) {
            float er[16];
            #pragma unroll
            for (int c = 0; c < 16; ++c) er[c] = E[lane][c4 * 16 + c];
            #pragma unroll
            for (int jj = 0; jj < 16; ++jj) {
                const float* w1r = w1 + (j0 + jj) * HD + c4 * 16;   // uniform -> s_load
                #pragma unroll
                for (int c = 0; c < 16; ++c)
                    acc[jj] = fmaf(er[c], w1r[c], acc[jj]);
            }
        }
        #pragma unroll
        for (int jj = 0; jj < 16; ++jj)
            T1[lane][j0 + jj] = fmaxf(acc[jj], 0.0f);
    }
    __syncthreads();

    // ---- Phase X: E + b2 + T1 @ w2^T; wave owns i in [wu*8, wu*8+8) ----
    {
        const int i0 = wu * 8;
        float acc[8];
        #pragma unroll
        for (int ii = 0; ii < 8; ++ii) acc[ii] = E[lane][i0 + ii] + b2[i0 + ii];
        #pragma unroll
        for (int c4 = 0; c4 < 8; ++c4) {
            float tr[16];
            #pragma unroll
            for (int c = 0; c < 16; ++c) tr[c] = T1[lane][c4 * 16 + c];
            #pragma unroll
            for (int ii = 0; ii < 8; ++ii) {
                const float* w2r = w2 + (i0 + ii) * 2 * HD + c4 * 16;  // s_load
                #pragma unroll
                for (int c = 0; c < 16; ++c)
                    acc[ii] = fmaf(tr[c], w2r[c], acc[ii]);
            }
        }
        #pragma unroll
        for (int ii = 0; ii < 8; ++ii) X[lane][i0 + ii] = acc[ii];
    }
    __syncthreads();

    // ---- Phase LN + gate score: 8 lanes per token (R8-verified) ----
    {
        const int v  = tid >> 3;   // token
        const int g  = tid & 7;
        const int k0 = g * 8;
        float xr[8];
        #pragma unroll
        for (int d = 0; d < 8; ++d) xr[d] = X[v][k0 + d];
        float s = 0.0f;
        #pragma unroll
        for (int d = 0; d < 8; ++d) s += xr[d];
        s += __shfl_xor(s, 1); s += __shfl_xor(s, 2); s += __shfl_xor(s, 4);
        const float mu = s * (1.0f / 64.0f);
        float vs = 0.0f;
        #pragma unroll
        for (int d = 0; d < 8; ++d) { float dd = xr[d] - mu; vs = fmaf(dd, dd, vs); }
        vs += __shfl_xor(vs, 1); vs += __shfl_xor(vs, 2); vs += __shfl_xor(vs, 4);
        const float rstd = rsqrtf(vs * (1.0f / 64.0f) + 1e-5f);
        float sp = 0.0f;
        #pragma unroll
        for (int d = 0; d < 8; ++d) {
            const int k = k0 + d;
            const float h = (xr[d] - mu) * rstd * gamma[k] + beta[k];
            H[v][k] = h;
            sp = fmaf(h, gate_w[k], sp);
        }
        sp += __shfl_xor(sp, 1); sp += __shfl_xor(sp, 2); sp += __shfl_xor(sp, 4);
        if (g == 0) score_s[v] = sp + gate_b[0];
    }
    __syncthreads();

    // ---- Phase QI/SK: H @ {qi,sk}_w^T + b; waves 0-3 qi, 4-7 sk ----
    {
        const bool isqi = (wu < 4);
        const int  i0   = (wu & 3) * 16;
        const float* Wm = isqi ? qi_w : sk_w;
        const float* Bm = isqi ? qi_b : sk_b;
        float acc[16];
        #pragma unroll
        for (int ii = 0; ii < 16; ++ii) acc[ii] = Bm[i0 + ii];
        #pragma unroll
        for (int c4 = 0; c4 < 4; ++c4) {
            float hr[16];
            #pragma unroll
            for (int c = 0; c < 16; ++c) hr[c] = H[lane][c4 * 16 + c];
            #pragma unroll
            for (int ii = 0; ii < 16; ++ii) {
                const float* Wr = Wm + (i0 + ii) * HD + c4 * 16;    // s_load
                #pragma unroll
                for (int c = 0; c < 16; ++c)
                    acc[ii] = fmaf(hr[c], Wr[c], acc[ii]);
            }
        }
        float (*DST)[65] = isqi ? QI : SK;
        #pragma unroll
        for (int ii = 0; ii < 16; ++ii) DST[lane][i0 + ii] = acc[ii];
    }
    __syncthreads();

    // ---- Phase R: histogram (each wave: its half-row into its own bin row) ----
    hist[w][lane] = 0;
    #pragma unroll
    for (int i = 0; i < 4; ++i) {
        atomicAdd(&hist[w][q[i].x], 1); atomicAdd(&hist[w][q[i].y], 1);
        atomicAdd(&hist[w][q[i].z], 1); atomicAdd(&hist[w][q[i].w], 1);
    }
    __syncthreads();                        // B1: both halves' hist visible

    // Attention: computed redundantly by wave pair (w, w+4) — identical values.
    const int last = seq[(size_t)row * LSEQ + (LSEQ - 1)];   // uniform s_load

    const float sc = score_s[lane];
    int rank = 0;
    #pragma unroll
    for (int u = 0; u < 64; ++u) {
        float su = __shfl(sc, u);
        if (su > sc || (su == sc && u < lane)) ++rank;
    }
    order_s[rw][rank] = lane;               // duplicate write, same value
    __syncthreads();                        // B2: order_s pinned

    const int tok  = order_s[rw][lane];     // token with rank 'lane'
    const int cntr = hist[rw][tok] + hist[rw + 4][tok];

    int inc = cntr;
    #pragma unroll
    for (int off = 1; off < 64; off <<= 1) {
        int v2 = __shfl_up(inc, off);
        if (lane >= off) inc += v2;
    }
    const int cum = inc - cntr;             // exclusive prefix in rank order
    #pragma unroll
    for (int s = 0; s < NSLOTS; ++s)
        if (s >= cum && s < cum + cntr) slot_s[rw][s] = tok;
    __syncthreads();                        // B3: slot_s pinned

    int st_[NSLOTS];
    #pragma unroll
    for (int s = 0; s < NSLOTS; ++s) st_[s] = slot_s[rw][s];

    const float scale = 0.125f;             // 1/sqrt(64)
    const float qk = QI[last][lane];

    float mrow[NSLOTS], skrow[NSLOTS];
    #pragma unroll
    for (int s = 0; s < NSLOTS; ++s) {
        mrow[s]  = H[st_[s]][lane];
        skrow[s] = SK[st_[s]][lane];
    }

    // Stage 1: r = softmax(slot_keys . q_init * scale)
    float p[NSLOTS];
    #pragma unroll
    for (int s = 0; s < NSLOTS; ++s) p[s] = skrow[s] * qk;
    #pragma unroll
    for (int off = 1; off < 64; off <<= 1) {
        #pragma unroll
        for (int s = 0; s < NSLOTS; ++s) p[s] += __shfl_xor(p[s], off);
    }
    #pragma unroll
    for (int s = 0; s < NSLOTS; ++s) p[s] *= scale;
    float mx = p[0];
    #pragma unroll
    for (int s = 1; s < NSLOTS; ++s) mx = fmaxf(mx, p[s]);
    float sum = 0.0f, r[NSLOTS];
    #pragma unroll
    for (int s = 0; s < NSLOTS; ++s) { r[s] = expf(p[s] - mx); sum += r[s]; }
    float inv = 1.0f / sum;
    float readk = 0.0f;
    #pragma unroll
    for (int s = 0; s < NSLOTS; ++s) readk = fmaf(r[s] * inv, mrow[s], readk);
    rbuf[rw][lane] = readk;                 // duplicate write, same value
    __syncthreads();                        // B4: read vector pinned

    // q_refined = q_init + qr_b + qr_w . read  (float4 on GLOBAL only)
    float qref = qk + qr_b[lane];
    {
        const float4* wr = (const float4*)(qr_w + lane * HD);
        #pragma unroll
        for (int j4 = 0; j4 < HD / 4; ++j4) {
            float4 a = wr[j4];
            qref = fmaf(a.x, rbuf[rw][4 * j4 + 0], qref);
            qref = fmaf(a.y, rbuf[rw][4 * j4 + 1], qref);
            qref = fmaf(a.z, rbuf[rw][4 * j4 + 2], qref);
            qref = fmaf(a.w, rbuf[rw][4 * j4 + 3], qref);
        }
    }

    // Stage 2
    float p2[NSLOTS];
    #pragma unroll
    for (int s = 0; s < NSLOTS; ++s) p2[s] = mrow[s] * qref;
    #pragma unroll
    for (int off = 1; off < 64; off <<= 1) {
        #pragma unroll
        for (int s = 0; s < NSLOTS; ++s) p2[s] += __shfl_xor(p2[s], off);
    }
    #pragma unroll
    for (int s = 0; s < NSLOTS; ++s) p2[s] *= scale;
    float mx2 = p2[0];
    #pragma unroll
    for (int s = 1; s < NSLOTS; ++s) mx2 = fmaxf(mx2, p2[s]);
    float sum2 = 0.0f, aa[NSLOTS];
    #pragma unroll
    for (int s = 0; s < NSLOTS; ++s) { aa[s] = expf(p2[s] - mx2); sum2 += aa[s]; }
    float inv2 = 1.0f / sum2;
    float pooled = 0.0f;
    #pragma unroll
    for (int s = 0; s < NSLOTS; ++s) pooled = fmaf(aa[s] * inv2, mrow[s], pooled);
    __syncthreads();                        // B5a: all readk reads done
    rbuf[rw][lane] = pooled;                // duplicate write, same value
    __syncthreads();                        // B5b: pooled vector pinned

    // out[row][v] = out_b[v] + out_w[v,:] . pooled  (duplicate store, same value)
    float acc = out_b[lane];
    {
        const float4* wo = (const float4*)(out_w + lane * HD);
        #pragma unroll
        for (int k4 = 0; k4 < HD / 4; ++k4) {
            float4 a = wo[k4];
            acc = fmaf(a.x, rbuf[rw][4 * k4 + 0], acc);
            acc = fmaf(a.y, rbuf[rw][4 * k4 + 1], acc);
            acc = fmaf(a.z, rbuf[rw][4 * k4 + 2], acc);
            acc = fmaf(a.w, rbuf[rw][4 * k4 + 3], acc);
        }
    }
    out[(size_t)row * HD + lane] = acc;
}

extern "C" void kernel_launch(void* const* d_in, const int* in_sizes, int n_in,
                              void* d_out, int out_size, void* d_ws, size_t ws_size,
                              hipStream_t stream) {
    const int*   seq    = (const int*)  d_in[0];
    const float* embed  = (const float*)d_in[1];
    const float* w1     = (const float*)d_in[2];
    const float* b1     = (const float*)d_in[3];
    const float* w2     = (const float*)d_in[4];
    const float* b2     = (const float*)d_in[5];
    const float* gamma  = (const float*)d_in[6];
    const float* beta   = (const float*)d_in[7];
    const float* gate_w = (const float*)d_in[8];
    const float* gate_b = (const float*)d_in[9];
    const float* qi_w   = (const float*)d_in[10];
    const float* qi_b   = (const float*)d_in[11];
    const float* sk_w   = (const float*)d_in[12];
    const float* sk_b   = (const float*)d_in[13];
    const float* qr_w   = (const float*)d_in[14];
    const float* qr_b   = (const float*)d_in[15];
    const float* out_w  = (const float*)d_in[16];
    const float* out_b  = (const float*)d_in[17];

    hipLaunchKernelGGL(fused_kernel, dim3(NBATCH / 4), dim3(512), 0, stream,
                       seq, embed, w1, b1, w2, b2, gamma, beta, gate_w, gate_b,
                       qi_w, qi_b, sk_w, sk_b, qr_w, qr_b, out_w, out_b,
                       (float*)d_out);
}